// Round 10
// baseline (329.974 us; speedup 1.0000x reference)
//
#include <hip/hip_runtime.h>

#define T_ 2048
#define HID_ 2048
#define H_ 16
#define KV_ 8
#define G_ 2
#define D_ 128
#define GH_ 128
#define BS_ 64
#define NB_ 32
#define START_ 409
#define TG0_ 384
#define SCALE_ 0.08838834764831845f  // 1/sqrt(128), also 1/sqrt(GH)
#define MFIX_ 8.0f  // fixed softmax max: |logit| <= 128*SCALE = 11.31 (q,k rmsnormed)

typedef __attribute__((ext_vector_type(8))) short short8_t;
typedef __attribute__((ext_vector_type(4))) float float4_t;
typedef __attribute__((ext_vector_type(8))) unsigned short ushort8_t;
typedef __attribute__((ext_vector_type(4))) unsigned short ushort4_t;

// ---------- helpers ----------
__device__ __forceinline__ float wave_sum(float v) {
#pragma unroll
  for (int o = 32; o > 0; o >>= 1) v += __shfl_xor(v, o, 64);
  return v;
}
__device__ __forceinline__ unsigned short f2bf(float x) {
  unsigned int u = __float_as_uint(x);
  unsigned int r = (u + 0x7fffu + ((u >> 16) & 1u)) >> 16;
  return (unsigned short)r;
}

// async global->LDS 16B/lane; LDS dest = wave-uniform base + lane*16
__device__ __forceinline__ void gload16(const void* g, void* l) {
  __builtin_amdgcn_global_load_lds((const __attribute__((address_space(1))) unsigned int*)g,
                                   (__attribute__((address_space(3))) unsigned int*)l, 16, 0, 0);
}

// ---------- 64x64 cast+transpose tile (device) ----------
__device__ __forceinline__ void castT_dev(const float* __restrict__ in,
                                          unsigned short* __restrict__ out, int K, int N,
                                          int ldin, int bx, int by,
                                          unsigned short (*tile)[72], int tid) {
  int k0 = by * 64, n0 = bx * 64;
  int tx = tid & 63, ty4 = tid >> 6;
#pragma unroll
  for (int i = 0; i < 16; ++i) {
    int ky = ty4 * 16 + i;
    tile[tx][ky] = f2bf(in[(size_t)(k0 + ky) * ldin + n0 + tx]);
  }
  __syncthreads();
#pragma unroll
  for (int i = 0; i < 16; ++i) {
    int ny = ty4 * 16 + i;
    out[(size_t)(n0 + ny) * K + k0 + tx] = tile[ny][tx];
  }
}

// ---------- fused prologue: hs cast + all weight cast-transposes in one launch ----------
__global__ __launch_bounds__(256) void prep_cast(const float* __restrict__ hs,
                                                 const float* __restrict__ Wq,
                                                 const float* __restrict__ Wk,
                                                 const float* __restrict__ Wv,
                                                 const float* __restrict__ Wo,
                                                 const float* __restrict__ gwq,
                                                 const float* __restrict__ gwk,
                                                 unsigned short* __restrict__ hsb,
                                                 unsigned short* __restrict__ WqkvT,
                                                 unsigned short* __restrict__ WoT,
                                                 unsigned short* __restrict__ gwqT,
                                                 unsigned short* __restrict__ gwkT) {
  __shared__ unsigned short tile[64][72];
  int id = blockIdx.x, tid = threadIdx.x;
  if (id < 4096) {  // hs -> bf16 flat (4096*256 = 1048576 float4s)
    int i = id * 256 + tid;
    float4 v = ((const float4*)hs)[i];
    ushort4_t o = {f2bf(v.x), f2bf(v.y), f2bf(v.z), f2bf(v.w)};
    *(ushort4_t*)(hsb + (size_t)i * 4) = o;
  } else if (id < 5120) {  // Wq: 32x32 tiles
    int t = id - 4096;
    castT_dev(Wq, WqkvT, 2048, 2048, 2048, t & 31, t >> 5, tile, tid);
  } else if (id < 5632) {  // Wk: 16x32
    int t = id - 5120;
    castT_dev(Wk, WqkvT + (size_t)2048 * 2048, 2048, 1024, 1024, t & 15, t >> 4, tile, tid);
  } else if (id < 6144) {  // Wv: 16x32
    int t = id - 5632;
    castT_dev(Wv, WqkvT + (size_t)3072 * 2048, 2048, 1024, 1024, t & 15, t >> 4, tile, tid);
  } else if (id < 7168) {  // Wo: 32x32
    int t = id - 6144;
    castT_dev(Wo, WoT, 2048, 2048, 2048, t & 31, t >> 5, tile, tid);
  } else if (id < 7172) {  // gwq: 2x2
    int t = id - 7168;
    castT_dev(gwq, gwqT, 128, 128, 128, t & 1, t >> 1, tile, tid);
  } else {  // gwk: 2x2
    int t = id - 7172;
    castT_dev(gwk, gwkT, 128, 128, 128, t & 1, t >> 1, tile, tid);
  }
}

// ---------- bf16 MFMA GEMM v4 body: BK=64, double-buffered single-barrier loop ----------
__device__ __forceinline__ void gemm_body(const unsigned short* __restrict__ A,
                                          const unsigned short* __restrict__ Bt,
                                          float* __restrict__ C,
                                          int M, int N, int K, int ldc, int bx, int by,
                                          unsigned short* As, unsigned short* Bs) {
  int tid = threadIdx.x;
  int wid = tid >> 6, lane = tid & 63;
  int quad = lane >> 4, l16 = lane & 15;
  int wm = wid & 1, wn = wid >> 1;
  int m0 = by * 128, n0 = bx * 128;
  const unsigned short* gA[4];
  const unsigned short* gB[4];
#pragma unroll
  for (int it = 0; it < 4; ++it) {
    int line = wid * 32 + it * 8 + (lane >> 3);
    int chunk = (lane & 7) ^ (line & 7);
    gA[it] = A + (size_t)(m0 + line) * K + chunk * 8;
    gB[it] = Bt + (size_t)(n0 + line) * K + chunk * 8;
  }
  float4_t acc[4][4];
#pragma unroll
  for (int i = 0; i < 4; ++i)
#pragma unroll
    for (int j = 0; j < 4; ++j) acc[i][j] = (float4_t){0.f, 0.f, 0.f, 0.f};
  int nk = K >> 6;
  // prologue: stage tile 0 into half 0
#pragma unroll
  for (int it = 0; it < 4; ++it) {
    gload16(gA[it], As + (wid * 32 + it * 8) * 64);
    gload16(gB[it], Bs + (wid * 32 + it * 8) * 64);
  }
  for (int t = 0; t < nk; ++t) {
    __syncthreads();  // tile t landed (barrier drains vmcnt); half (t+1)&1 free
    if (t + 1 < nk) {
      int bo = ((t + 1) & 1) * 8192;
#pragma unroll
      for (int it = 0; it < 4; ++it) {
        gload16(gA[it] + (t + 1) * 64, As + bo + (wid * 32 + it * 8) * 64);
        gload16(gB[it] + (t + 1) * 64, Bs + bo + (wid * 32 + it * 8) * 64);
      }
    }
    const unsigned short* Asc = As + (t & 1) * 8192;
    const unsigned short* Bsc = Bs + (t & 1) * 8192;
    short8_t a[2][4], b[2][4];
#pragma unroll
    for (int ks = 0; ks < 2; ++ks) {
      int sw = ((ks * 4 + quad) ^ (l16 & 7)) * 8;
#pragma unroll
      for (int i = 0; i < 4; ++i) {
        a[ks][i] = *(const short8_t*)&Asc[(wm * 64 + i * 16 + l16) * 64 + sw];
        b[ks][i] = *(const short8_t*)&Bsc[(wn * 64 + i * 16 + l16) * 64 + sw];
      }
    }
#pragma unroll
    for (int ks = 0; ks < 2; ++ks)
#pragma unroll
      for (int i = 0; i < 4; ++i)
#pragma unroll
        for (int j = 0; j < 4; ++j)
          acc[i][j] = __builtin_amdgcn_mfma_f32_16x16x32_bf16(a[ks][i], b[ks][j], acc[i][j], 0, 0, 0);
  }
#pragma unroll
  for (int i = 0; i < 4; ++i)
#pragma unroll
    for (int j = 0; j < 4; ++j)
#pragma unroll
      for (int reg = 0; reg < 4; ++reg)
        C[(size_t)(m0 + wm * 64 + i * 16 + quad * 4 + reg) * ldc + n0 + wn * 64 + j * 16 + l16] =
            acc[i][j][reg];
}

// XCD-aware swizzle (T1): each XCD gets a contiguous id-chunk -> 2 consecutive by
// panels live in its private L2 instead of all 16. Requires nwg % 8 == 0 (512, 256 ok).
__global__ __launch_bounds__(256) void gemm_bf16_v3(const unsigned short* __restrict__ A,
                                                    const unsigned short* __restrict__ Bt,
                                                    float* __restrict__ C,
                                                    int M, int N, int K, int ldc) {
  __shared__ unsigned short As[2 * 128 * 64];
  __shared__ unsigned short Bs[2 * 128 * 64];
  int lin = blockIdx.y * gridDim.x + blockIdx.x;
  int nwg = gridDim.x * gridDim.y;
  int q = nwg >> 3;
  int v = (lin & 7) * q + (lin >> 3);
  int bx = v % gridDim.x, by = v / gridDim.x;
  gemm_body(A, Bt, C, M, N, K, ldc, bx, by, As, Bs);
}

// merged gate gemms: y<104 -> gq (13312x128x128), else -> gk (256x128x128)
__global__ __launch_bounds__(256) void gemm_gates(const unsigned short* __restrict__ Aq,
                                                  const unsigned short* __restrict__ Bq,
                                                  float* __restrict__ Cq,
                                                  const unsigned short* __restrict__ Ak,
                                                  const unsigned short* __restrict__ Bk,
                                                  float* __restrict__ Ck) {
  __shared__ unsigned short As[2 * 128 * 64];
  __shared__ unsigned short Bs[2 * 128 * 64];
  int y = blockIdx.y;
  if (y < 104)
    gemm_body(Aq, Bq, Cq, 13312, 128, 128, 128, 0, y, As, Bs);
  else
    gemm_body(Ak, Bk, Ck, 256, 128, 128, 128, 0, y - 104, As, Bs);
}

// ---------- fused q/k rmsnorm + rope (+q pool); grid (T, 8): each block does its kv's
// q-pair phase then k phase (halves dispatch count vs (T,16)) ----------
__global__ __launch_bounds__(128) void norm_rope_fused(const float* __restrict__ qkvf,
                                                       const float* __restrict__ qw,
                                                       const float* __restrict__ kw,
                                                       const float* __restrict__ cosT,
                                                       const float* __restrict__ sinT,
                                                       unsigned short* __restrict__ qbf,
                                                       unsigned short* __restrict__ qpool_bf,
                                                       unsigned short* __restrict__ kbf,
                                                       float* __restrict__ knorm) {
  int t = blockIdx.x, d = threadIdx.x;
  int kv = blockIdx.y;
  float cv = cosT[t * D_ + d], sv = sinT[t * D_ + d];
  // ---- phase 1: q pair ----
  {
    size_t i0 = (size_t)t * 4096 + (kv * G_) * D_ + d;
    float x0 = qkvf[i0], x1 = qkvf[i0 + D_];
    __shared__ float sred[2][2];
    float s0 = wave_sum(x0 * x0), s1 = wave_sum(x1 * x1);
    if ((d & 63) == 0) { sred[0][d >> 6] = s0; sred[1][d >> 6] = s1; }
    __syncthreads();
    float wv = qw[d];
    float n0 = x0 * rsqrtf((sred[0][0] + sred[0][1]) * (1.f / D_) + 1e-6f) * wv;
    float n1 = x1 * rsqrtf((sred[1][0] + sred[1][1]) * (1.f / D_) + 1e-6f) * wv;
    if (t >= TG0_) qpool_bf[((size_t)(t - TG0_) * KV_ + kv) * D_ + d] = f2bf(0.5f * (n0 + n1));
    __shared__ float sh[2][D_];
    sh[0][d] = n0; sh[1][d] = n1;
    __syncthreads();
    float r0 = (d < 64) ? -sh[0][d + 64] : sh[0][d - 64];
    float r1 = (d < 64) ? -sh[1][d + 64] : sh[1][d - 64];
    qbf[((size_t)(t * H_) + kv * G_) * D_ + d] = f2bf(n0 * cv + r0 * sv);
    qbf[((size_t)(t * H_) + kv * G_ + 1) * D_ + d] = f2bf(n1 * cv + r1 * sv);
  }
  __syncthreads();
  // ---- phase 2: k ----
  {
    float x = qkvf[(size_t)t * 4096 + 2048 + kv * D_ + d];
    __shared__ float sredk[2];
    float s0 = wave_sum(x * x);
    if ((d & 63) == 0) sredk[d >> 6] = s0;
    __syncthreads();
    float nk = x * rsqrtf((sredk[0] + sredk[1]) * (1.f / D_) + 1e-6f) * kw[d];
    knorm[(size_t)(t * KV_ + kv) * D_ + d] = nk;
    __shared__ float shk[D_];
    shk[d] = nk;
    __syncthreads();
    float rot = (d < 64) ? -shk[d + 64] : shk[d - 64];
    kbf[(size_t)(t * KV_ + kv) * D_ + d] = f2bf(nk * cv + rot * sv);
  }
}

// ---------- merged: castT for v (id<512) + k_blk mean (id>=512, 2 tasks/block) ----------
__global__ __launch_bounds__(256) void castT_kblk(const float* __restrict__ qkvf,
                                                  unsigned short* __restrict__ vt,
                                                  const float* __restrict__ knorm,
                                                  unsigned short* __restrict__ kblk_bf) {
  __shared__ unsigned short tile[64][72];
  int id = blockIdx.x, tid = threadIdx.x;
  if (id < 512) {
    castT_dev(qkvf + 3072, vt, T_, 1024, 4096, id & 15, id >> 4, tile, tid);
  } else {
    int task = (id - 512) * 2 + (tid >> 7);  // [0,256): n*8+kv
    int n = task >> 3, kv = task & 7, d = tid & 127;
    float s = 0.f;
    for (int i = 0; i < BS_; ++i) s += knorm[((size_t)(n * BS_ + i) * KV_ + kv) * D_ + d];
    kblk_bf[(size_t)(n * KV_ + kv) * D_ + d] = f2bf(s * (1.f / BS_));
  }
}

// ---------- fused rope for gk (rows<NB) and gq (rows>=NB, table offset TG0) ----------
__global__ __launch_bounds__(128) void rope_g_fused(float* __restrict__ gq, float* __restrict__ gk,
                                                    const float* __restrict__ cosG,
                                                    const float* __restrict__ sinG,
                                                    const float* __restrict__ cosB,
                                                    const float* __restrict__ sinB) {
  int r = blockIdx.x, kvh = blockIdx.y, d = threadIdx.x;
  float* x;
  size_t base;
  float c_, s_;
  if (r < NB_) {
    x = gk;
    base = (size_t)(r * KV_ + kvh) * GH_;
    c_ = cosB[r * GH_ + d]; s_ = sinB[r * GH_ + d];
  } else {
    int rr = r - NB_;
    x = gq;
    base = (size_t)(rr * KV_ + kvh) * GH_;
    c_ = cosG[(size_t)(TG0_ + rr) * GH_ + d]; s_ = sinG[(size_t)(TG0_ + rr) * GH_ + d];
  }
  __shared__ float sh[GH_];
  sh[d] = x[base + d];
  __syncthreads();
  float rot = (d < 64) ? -sh[d + 64] : sh[d - 64];
  x[base + d] = sh[d] * c_ + rot * s_;
}

// ---------- MFMA flash attention v7: GQA head-merge + shared K/V reads, FLAT chunk
// assignment. Per kv, the 528 causal (tile,chunk) pairs are enumerated flat; block yy
// takes global chunks [528*yy/64, 528*(yy+1)/64) -> every block 8-9 chunks (round-7's
// {1,16} pairing starved CUs; round-8's 640-block version had a straggler tail; this
// keeps EXACTLY 512 blocks = 2/CU resident AND equal durations). K/V staging depends
// only on the key-chunk index, so the dbuf gload16 pipeline runs continuously across
// tile boundaries; Q/accumulators/epilogue are per tile-segment (~96 segments/kv).
// Fixed-max softmax -> additive partials via atomicAdd into zeroed o_acc/l_acc. ----------
__global__ __launch_bounds__(256, 2) void attn_mfma(const unsigned short* __restrict__ qbf,
                                                    const unsigned short* __restrict__ kbf,
                                                    const unsigned short* __restrict__ vt,
                                                    float* __restrict__ pooled,
                                                    float* __restrict__ o_acc,
                                                    float* __restrict__ l_acc) {
  int kv = blockIdx.x;
  int yy = blockIdx.y;  // [0,64)
  const int TC = 528;   // total chunks per kv: sum_{t=0}^{31} (t+1)
  int g = (TC * yy) >> 6;
  int g_hi = (TC * (yy + 1)) >> 6;
  // find starting tile: largest t with t(t+1)/2 <= g
  int tile = 0, tb = 0;
  while (tb + tile + 1 <= g) { tb += tile + 1; ++tile; }
  int c = g - tb;

  int tid = threadIdx.x;
  int wid = tid >> 6, lane = tid & 63;
  int quad = lane >> 4, l16 = lane & 15;
  __shared__ unsigned short Ks[2][64 * 128];   // [key][chunk16 ^ (key&7)]
  __shared__ unsigned short Vs[2][128 * 64];   // [d][chunk16 ^ (d&7)]
  __shared__ unsigned short Ps[8][16 * 64];    // [wave*2+head][row][col8 ^ (row&7)]

  const unsigned short* kbase[4];
  const unsigned short* vbase[4];
#pragma unroll
  for (int it = 0; it < 4; ++it) {
    int seg = wid * 4 + it;
    int krow = seg * 4 + (lane >> 4);
    int kchk = lane & 15;
    kbase[it] = kbf + ((size_t)krow * KV_ + kv) * D_ + ((kchk ^ (krow & 7)) << 3);
    int vrow = seg * 8 + (lane >> 3);
    int vchk = lane & 7;
    vbase[it] = vt + (size_t)(kv * 128 + vrow) * T_ + ((vchk ^ (vrow & 7)) << 3);
  }

  const short one_bf = (short)0x3F80;
  short8_t ones = {one_bf, one_bf, one_bf, one_bf, one_bf, one_bf, one_bf, one_bf};

  // prologue: stage first chunk into buffer 0
  int buf = 0;
#pragma unroll
  for (int it = 0; it < 4; ++it) {
    gload16(kbase[it] + (size_t)c * 65536, &Ks[0][(wid * 4 + it) * 512]);
    gload16(vbase[it] + c * 64, &Vs[0][(wid * 4 + it) * 512]);
  }

  while (g < g_hi) {
    // ---- segment start: (tile, c) ----
    int t0 = tile * 64;
    int tq = t0 + wid * 16 + l16;
    short8_t qf[2][4];
#pragma unroll
    for (int hh = 0; hh < 2; ++hh)
#pragma unroll
      for (int kb = 0; kb < 4; ++kb)
        qf[hh][kb] = *(const short8_t*)&qbf[((size_t)tq * H_ + kv * G_ + hh) * D_ + kb * 32 + quad * 8];
    int tbase = t0 + wid * 16 + quad * 4;
    float l_[2][4] = {};
    float pacc[2][2][4] = {};  // [head][half][reg]
    float4_t o[2][8];
#pragma unroll
    for (int hh = 0; hh < 2; ++hh)
#pragma unroll
      for (int j = 0; j < 8; ++j) o[hh][j] = (float4_t){0.f, 0.f, 0.f, 0.f};
    int c_start = c;
    bool segEnd = false;
    while (!segEnd) {
      __syncthreads();  // current chunk landed in buf (barrier drains vmcnt)
      if (g + 1 < g_hi) {
        int nc = (c + 1 <= tile) ? c + 1 : 0;  // next chunk (may be next tile's chunk 0)
        int b = buf ^ 1;
#pragma unroll
        for (int it = 0; it < 4; ++it) {
          gload16(kbase[it] + (size_t)nc * 65536, &Ks[b][(wid * 4 + it) * 512]);
          gload16(vbase[it] + nc * 64, &Vs[b][(wid * 4 + it) * 512]);
        }
      }
      const unsigned short* Ksc = Ks[buf];
      const unsigned short* Vsc = Vs[buf];
      int half = c >> 4, cl = c & 15;

      // ---- QK^T for BOTH heads off one kf read ----
      float4_t s[2][4];
#pragma unroll
      for (int j = 0; j < 4; ++j) {
        float4_t a0 = (float4_t){0.f, 0.f, 0.f, 0.f};
        float4_t a1 = (float4_t){0.f, 0.f, 0.f, 0.f};
#pragma unroll
        for (int kb = 0; kb < 4; ++kb) {
          short8_t kf = *(const short8_t*)&Ksc[(j * 16 + l16) * 128 + (((kb * 4 + quad) ^ (l16 & 7)) << 3)];
          a0 = __builtin_amdgcn_mfma_f32_16x16x32_bf16(qf[0][kb], kf, a0, 0, 0, 0);
          a1 = __builtin_amdgcn_mfma_f32_16x16x32_bf16(qf[1][kb], kf, a1, 0, 0, 0);
        }
        s[0][j] = a0;
        s[1][j] = a1;
      }
      // ---- p = exp(logit - MFIX); causal mask only on diagonal chunk ----
#pragma unroll
      for (int hh = 0; hh < 2; ++hh) {
        if (c == tile) {
#pragma unroll
          for (int reg = 0; reg < 4; ++reg) {
            int trow = tbase + reg;
#pragma unroll
            for (int j = 0; j < 4; ++j) {
              float p = __expf(s[hh][j][reg] * SCALE_ - MFIX_);
              s[hh][j][reg] = (c * 64 + j * 16 + l16 <= trow) ? p : 0.f;
            }
          }
        } else {
#pragma unroll
          for (int j = 0; j < 4; ++j)
#pragma unroll
            for (int reg = 0; reg < 4; ++reg)
              s[hh][j][reg] = __expf(s[hh][j][reg] * SCALE_ - MFIX_);
        }
        // write P (C layout) -> per-wave-per-head LDS, XOR-swizzled stride 64
#pragma unroll
        for (int j = 0; j < 4; ++j)
#pragma unroll
          for (int reg = 0; reg < 4; ++reg) {
            int r = quad * 4 + reg;
            Ps[wid * 2 + hh][r * 64 + ((j * 16 + l16) ^ ((r & 7) << 3))] = f2bf(s[hh][j][reg]);
          }
      }
      // ---- PV + row-sum for BOTH heads off one vf read ----
      float4_t pool[2] = {(float4_t){0.f, 0.f, 0.f, 0.f}, (float4_t){0.f, 0.f, 0.f, 0.f}};
#pragma unroll
      for (int ks = 0; ks < 2; ++ks) {
        int psw = l16 * 64 + (((ks * 4 + quad) ^ (l16 & 7)) << 3);
        short8_t pf0 = *(const short8_t*)&Ps[wid * 2 + 0][psw];
        short8_t pf1 = *(const short8_t*)&Ps[wid * 2 + 1][psw];
        pool[0] = __builtin_amdgcn_mfma_f32_16x16x32_bf16(pf0, ones, pool[0], 0, 0, 0);
        pool[1] = __builtin_amdgcn_mfma_f32_16x16x32_bf16(pf1, ones, pool[1], 0, 0, 0);
#pragma unroll
        for (int jt = 0; jt < 8; ++jt) {
          short8_t vf = *(const short8_t*)&Vsc[(jt * 16 + l16) * 64 + (((ks * 4 + quad) ^ (l16 & 7)) << 3)];
          o[0][jt] = __builtin_amdgcn_mfma_f32_16x16x32_bf16(pf0, vf, o[0][jt], 0, 0, 0);
          o[1][jt] = __builtin_amdgcn_mfma_f32_16x16x32_bf16(pf1, vf, o[1][jt], 0, 0, 0);
        }
      }
#pragma unroll
      for (int hh = 0; hh < 2; ++hh)
#pragma unroll
        for (int reg = 0; reg < 4; ++reg) {
          l_[hh][reg] += pool[hh][reg];
          if (l16 == cl) pacc[hh][half][reg] = pool[hh][reg];
        }
      buf ^= 1;
      ++g;
      if (g < g_hi && c < tile) ++c; else segEnd = true;
    }
    // ---- segment epilogue: chunks [c_start, c_end) of this tile ----
    int c_end = c + 1;
#pragma unroll
    for (int hh = 0; hh < 2; ++hh) {
      int h = kv * G_ + hh;
      // pooled RAW, disjoint columns per segment
#pragma unroll
      for (int reg = 0; reg < 4; ++reg) {
        int trow = tbase + reg;
        if (l16 >= c_start && l16 < c_end)
          pooled[((size_t)h * T_ + trow) * NB_ + l16] = pacc[hh][0][reg];
        if (16 + l16 >= c_start && 16 + l16 < c_end)
          pooled[((size_t)h * T_ + trow) * NB_ + 16 + l16] = pacc[hh][1][reg];
      }
      // o/l partials: fp32 atomic accumulate (segments of a tile run concurrently)
#pragma unroll
      for (int jt = 0; jt < 8; ++jt)
#pragma unroll
        for (int reg = 0; reg < 4; ++reg)
          atomicAdd(&o_acc[(((size_t)h * T_) + tbase + reg) * D_ + jt * 16 + l16], o[hh][jt][reg]);
      if (l16 == 0) {
#pragma unroll
        for (int reg = 0; reg < 4; ++reg)
          atomicAdd(&l_acc[(size_t)h * T_ + tbase + reg], l_[hh][reg]);
      }
    }
    if (g < g_hi) { ++tile; c = 0; }
  }
}

// ---------- gate loss body, LDS-staged gk (round-7 proven) ----------
__device__ __forceinline__ void gate_loss_body(const float* __restrict__ gq,
                                               const float* __restrict__ gk,
                                               const float* __restrict__ pooled,
                                               const float* __restrict__ l_acc,
                                               float* __restrict__ klsum,
                                               int kv, int yblk, float4* gks4) {
  int tid = threadIdx.x;
  // cooperative stage: 1024 float4s, 4 per thread
#pragma unroll
  for (int p = 0; p < 4; ++p) {
    int f = p * 256 + tid;
    int n = f >> 5, d4 = f & 31;
    gks4[n * 32 + (d4 ^ (n & 7))] =
        *(const float4*)(gk + ((size_t)n * KV_ + kv) * GH_ + d4 * 4);
  }
  __syncthreads();
  int sub = tid >> 5;  // 0..7
  int n = tid & 31;
  int tloc = yblk * 8 + sub;
  bool act = tloc < (T_ - START_);
  int t = START_ + (act ? tloc : 0);
  const float4* a = (const float4*)(gq + ((size_t)(t - TG0_) * KV_ + kv) * GH_);
  float dot = 0.f;
#pragma unroll
  for (int d4 = 0; d4 < 32; ++d4) {
    float4 av = a[d4];
    float4 bv = gks4[n * 32 + (d4 ^ (n & 7))];
    dot += av.x * bv.x + av.y * bv.y + av.z * bv.z + av.w * bv.w;
  }
  bool valid = (t / BS_) >= n;
  float score = valid ? dot * SCALE_ : -1e9f;
  float M = score;
#pragma unroll
  for (int o = 16; o > 0; o >>= 1) M = fmaxf(M, __shfl_xor(M, o, 64));
  float e = __expf(score - M);
  float Z = e;
#pragma unroll
  for (int o = 16; o > 0; o >>= 1) Z += __shfl_xor(Z, o, 64);
  float logZ = M + logf(Z);
  float g = 0.f;
  if (valid) {
    float rl0 = 1.f / l_acc[(size_t)(kv * G_) * T_ + t];
    float rl1 = 1.f / l_acc[(size_t)(kv * G_ + 1) * T_ + t];
    float p0 = pooled[((size_t)(kv * G_) * T_ + t) * NB_ + n] * rl0;
    float p1 = pooled[((size_t)(kv * G_ + 1) * T_ + t) * NB_ + n] * rl1;
    g = fmaxf(p0, p1);
  }
  float gs = g;
#pragma unroll
  for (int o = 16; o > 0; o >>= 1) gs += __shfl_xor(gs, o, 64);
  float tgt = g / (gs + 1e-9f);
  float kl = (tgt > 0.f) ? tgt * (logf(tgt) - (score - logZ)) : 0.f;
  float ks = kl;
#pragma unroll
  for (int o = 16; o > 0; o >>= 1) ks += __shfl_xor(ks, o, 64);
  if (n == 0 && act) klsum[kv * (T_ - START_) + tloc] = ks;
}

// ---------- merged: gate loss (id<1640, dispatched first) + attn_combine (id>=1640) ----------
__global__ __launch_bounds__(256) void combine_gate(const float* __restrict__ o_acc,
                                                    const float* __restrict__ l_acc,
                                                    unsigned short* __restrict__ attnb,
                                                    const float* __restrict__ gq,
                                                    const float* __restrict__ gk,
                                                    const float* __restrict__ pooled,
                                                    float* __restrict__ klsum) {
  __shared__ float4 gks4[1024];
  int id = blockIdx.x;
  if (id < 1640) {
    gate_loss_body(gq, gk, pooled, l_acc, klsum, id & 7, id >> 3, gks4);
  } else {
    int gid = (id - 1640) * 256 + threadIdx.x;  // [0, 1048576) float4 units
    int row = gid >> 5, q4 = gid & 31;          // row = h*2048 + t
    int h = row >> 11, t = row & 2047;
    float inv = 1.f / l_acc[row];
    float4 a = ((const float4*)o_acc)[gid];
    ushort4_t ov = {f2bf(a.x * inv), f2bf(a.y * inv), f2bf(a.z * inv), f2bf(a.w * inv)};
    *(ushort4_t*)(attnb + (size_t)t * (H_ * D_) + h * D_ + q4 * 4) = ov;
  }
}

__global__ __launch_bounds__(256) void finalize_loss(const float* __restrict__ klsum,
                                                     float* __restrict__ out) {
  const int n = KV_ * (T_ - START_);
  float s = 0.f;
  for (int i = threadIdx.x; i < n; i += 256) s += klsum[i];
  s = wave_sum(s);
  __shared__ float sh[4];
  if ((threadIdx.x & 63) == 0) sh[threadIdx.x >> 6] = s;
  __syncthreads();
  if (threadIdx.x == 0)
    out[0] = (sh[0] + sh[1] + sh[2] + sh[3]) * (1.f / ((float)(T_ - START_) * NB_));
}

extern "C" void kernel_launch(void* const* d_in, const int* in_sizes, int n_in,
                              void* d_out, int out_size, void* d_ws, size_t ws_size,
                              hipStream_t stream) {
  const float* hs   = (const float*)d_in[0];
  const float* Wq   = (const float*)d_in[1];
  const float* Wk   = (const float*)d_in[2];
  const float* Wv   = (const float*)d_in[3];
  const float* Wo   = (const float*)d_in[4];
  const float* qw   = (const float*)d_in[5];
  const float* kw   = (const float*)d_in[6];
  const float* gwq  = (const float*)d_in[7];
  const float* gwk  = (const float*)d_in[8];
  const float* cosT = (const float*)d_in[9];
  const float* sinT = (const float*)d_in[10];
  const float* cosG = (const float*)d_in[11];
  const float* sinG = (const float*)d_in[12];
  const float* cosB = (const float*)d_in[13];
  const float* sinB = (const float*)d_in[14];
  float* out = (float*)d_out;
  float* ws = (float*)d_ws;
  const size_t MEG = 1048576;

  // ---- workspace layout (float offsets), lifetime-aliased ----
  float*          qkvf     = ws;                                 // [0,8M): [T][4096] fp32
  unsigned short* attnb    = (unsigned short*)ws;                //   alias after qkvf consumed
  float*          pooled   = ws + 2 * MEG;                       //   alias
  float*          klsum    = ws + 3 * MEG;                       //   alias (13112 floats)
  float*          l_acc    = ws + 3 * MEG + 65536;               //   alias: [H][T] row-sum l
  float*          o_acc    = ws + 4 * MEG;                       //   alias: [H][T][128] fp32 (16MB)
  unsigned short* WqkvT    = (unsigned short*)(ws + 8 * MEG);    // [8M,12M): 8M ushorts
  unsigned short* qbf      = WqkvT;                              //   alias after qkv gemm
  unsigned short* kbf      = WqkvT + 4 * MEG;
  unsigned short* vt       = WqkvT + 6 * MEG;
  unsigned short* hsb      = (unsigned short*)(ws + 12 * MEG);   // [12M,14M)
  float*          knorm    = ws + 12 * MEG;                      //   alias after qkv gemm
  unsigned short* WoT      = (unsigned short*)(ws + 14 * MEG);   // [14M,16M)
  unsigned short* qpool_bf = (unsigned short*)(ws + 16 * MEG);   // [16M,...)
  float*          gq       = ws + 17 * MEG;
  unsigned short* kblk_bf  = (unsigned short*)(ws + 18 * MEG + 786432);
  float*          gk       = ws + 18 * MEG + 819200;
  unsigned short* gwqT     = (unsigned short*)(ws + 18 * MEG + 851968);
  unsigned short* gwkT     = (unsigned short*)(ws + 18 * MEG + 860160);

  prep_cast<<<7176, 256, 0, stream>>>(hs, Wq, Wk, Wv, Wo, gwq, gwk, hsb, WqkvT, WoT, gwqT, gwkT);
  gemm_bf16_v3<<<dim3(32, 16), 256, 0, stream>>>(hsb, WqkvT, qkvf, 2048, 4096, 2048, 4096);
  norm_rope_fused<<<dim3(T_, 8), 128, 0, stream>>>(qkvf, qw, kw, cosT, sinT, qbf, qpool_bf,
                                                   kbf, knorm);
  castT_kblk<<<640, 256, 0, stream>>>(qkvf, vt, knorm, kblk_bf);
  // qkvf fully consumed -> zero the atomic accumulators living in its footprint
  hipMemsetAsync(o_acc, 0, (size_t)4 * MEG * sizeof(float), stream);
  hipMemsetAsync(l_acc, 0, (size_t)H_ * T_ * sizeof(float), stream);
  gemm_gates<<<dim3(1, 106), 256, 0, stream>>>(qpool_bf, gwqT, gq, kblk_bf, gwkT, gk);
  rope_g_fused<<<dim3(NB_ + (T_ - TG0_), KV_), 128, 0, stream>>>(gq, gk, cosG, sinG, cosB, sinB);
  attn_mfma<<<dim3(KV_, 64), 256, 0, stream>>>(qbf, kbf, vt, pooled, o_acc, l_acc);
  combine_gate<<<1640 + 4096, 256, 0, stream>>>(o_acc, l_acc, attnb, gq, gk, pooled, klsum);
  gemm_bf16_v3<<<dim3(16, 16), 256, 0, stream>>>(attnb, WoT, out, 2048, 2048, 2048, 2048);
  finalize_loss<<<1, 256, 0, stream>>>(klsum, out + (size_t)T_ * HID_);
}

// Round 11
// 303.938 us; speedup vs baseline: 1.0857x; 1.0857x over previous
//
#include <hip/hip_runtime.h>

#define T_ 2048
#define HID_ 2048
#define H_ 16
#define KV_ 8
#define G_ 2
#define D_ 128
#define GH_ 128
#define BS_ 64
#define NB_ 32
#define START_ 409
#define TG0_ 384
#define SCALE_ 0.08838834764831845f  // 1/sqrt(128), also 1/sqrt(GH)
#define MFIX_ 8.0f  // fixed softmax max: |logit| <= 128*SCALE = 11.31 (q,k rmsnormed)

typedef __attribute__((ext_vector_type(8))) short short8_t;
typedef __attribute__((ext_vector_type(4))) float float4_t;
typedef __attribute__((ext_vector_type(8))) unsigned short ushort8_t;
typedef __attribute__((ext_vector_type(4))) unsigned short ushort4_t;

// ---------- helpers ----------
__device__ __forceinline__ float wave_sum(float v) {
#pragma unroll
  for (int o = 32; o > 0; o >>= 1) v += __shfl_xor(v, o, 64);
  return v;
}
__device__ __forceinline__ unsigned short f2bf(float x) {
  unsigned int u = __float_as_uint(x);
  unsigned int r = (u + 0x7fffu + ((u >> 16) & 1u)) >> 16;
  return (unsigned short)r;
}

// async global->LDS 16B/lane; LDS dest = wave-uniform base + lane*16
__device__ __forceinline__ void gload16(const void* g, void* l) {
  __builtin_amdgcn_global_load_lds((const __attribute__((address_space(1))) unsigned int*)g,
                                   (__attribute__((address_space(3))) unsigned int*)l, 16, 0, 0);
}

// ---------- 64x64 cast+transpose tile (device) ----------
__device__ __forceinline__ void castT_dev(const float* __restrict__ in,
                                          unsigned short* __restrict__ out, int K, int N,
                                          int ldin, int bx, int by,
                                          unsigned short (*tile)[72], int tid) {
  int k0 = by * 64, n0 = bx * 64;
  int tx = tid & 63, ty4 = tid >> 6;
#pragma unroll
  for (int i = 0; i < 16; ++i) {
    int ky = ty4 * 16 + i;
    tile[tx][ky] = f2bf(in[(size_t)(k0 + ky) * ldin + n0 + tx]);
  }
  __syncthreads();
#pragma unroll
  for (int i = 0; i < 16; ++i) {
    int ny = ty4 * 16 + i;
    out[(size_t)(n0 + ny) * K + k0 + tx] = tile[ny][tx];
  }
}

// ---------- fused prologue: hs cast + all weight cast-transposes in one launch ----------
__global__ __launch_bounds__(256) void prep_cast(const float* __restrict__ hs,
                                                 const float* __restrict__ Wq,
                                                 const float* __restrict__ Wk,
                                                 const float* __restrict__ Wv,
                                                 const float* __restrict__ Wo,
                                                 const float* __restrict__ gwq,
                                                 const float* __restrict__ gwk,
                                                 unsigned short* __restrict__ hsb,
                                                 unsigned short* __restrict__ WqkvT,
                                                 unsigned short* __restrict__ WoT,
                                                 unsigned short* __restrict__ gwqT,
                                                 unsigned short* __restrict__ gwkT) {
  __shared__ unsigned short tile[64][72];
  int id = blockIdx.x, tid = threadIdx.x;
  if (id < 4096) {  // hs -> bf16 flat (4096*256 = 1048576 float4s)
    int i = id * 256 + tid;
    float4 v = ((const float4*)hs)[i];
    ushort4_t o = {f2bf(v.x), f2bf(v.y), f2bf(v.z), f2bf(v.w)};
    *(ushort4_t*)(hsb + (size_t)i * 4) = o;
  } else if (id < 5120) {  // Wq: 32x32 tiles
    int t = id - 4096;
    castT_dev(Wq, WqkvT, 2048, 2048, 2048, t & 31, t >> 5, tile, tid);
  } else if (id < 5632) {  // Wk: 16x32
    int t = id - 5120;
    castT_dev(Wk, WqkvT + (size_t)2048 * 2048, 2048, 1024, 1024, t & 15, t >> 4, tile, tid);
  } else if (id < 6144) {  // Wv: 16x32
    int t = id - 5632;
    castT_dev(Wv, WqkvT + (size_t)3072 * 2048, 2048, 1024, 1024, t & 15, t >> 4, tile, tid);
  } else if (id < 7168) {  // Wo: 32x32
    int t = id - 6144;
    castT_dev(Wo, WoT, 2048, 2048, 2048, t & 31, t >> 5, tile, tid);
  } else if (id < 7172) {  // gwq: 2x2
    int t = id - 7168;
    castT_dev(gwq, gwqT, 128, 128, 128, t & 1, t >> 1, tile, tid);
  } else {  // gwk: 2x2
    int t = id - 7172;
    castT_dev(gwk, gwkT, 128, 128, 128, t & 1, t >> 1, tile, tid);
  }
}

// ---------- bf16 MFMA GEMM v4 body: BK=64, double-buffered single-barrier loop ----------
__device__ __forceinline__ void gemm_body(const unsigned short* __restrict__ A,
                                          const unsigned short* __restrict__ Bt,
                                          float* __restrict__ C,
                                          int M, int N, int K, int ldc, int bx, int by,
                                          unsigned short* As, unsigned short* Bs) {
  int tid = threadIdx.x;
  int wid = tid >> 6, lane = tid & 63;
  int quad = lane >> 4, l16 = lane & 15;
  int wm = wid & 1, wn = wid >> 1;
  int m0 = by * 128, n0 = bx * 128;
  const unsigned short* gA[4];
  const unsigned short* gB[4];
#pragma unroll
  for (int it = 0; it < 4; ++it) {
    int line = wid * 32 + it * 8 + (lane >> 3);
    int chunk = (lane & 7) ^ (line & 7);
    gA[it] = A + (size_t)(m0 + line) * K + chunk * 8;
    gB[it] = Bt + (size_t)(n0 + line) * K + chunk * 8;
  }
  float4_t acc[4][4];
#pragma unroll
  for (int i = 0; i < 4; ++i)
#pragma unroll
    for (int j = 0; j < 4; ++j) acc[i][j] = (float4_t){0.f, 0.f, 0.f, 0.f};
  int nk = K >> 6;
  // prologue: stage tile 0 into half 0
#pragma unroll
  for (int it = 0; it < 4; ++it) {
    gload16(gA[it], As + (wid * 32 + it * 8) * 64);
    gload16(gB[it], Bs + (wid * 32 + it * 8) * 64);
  }
  for (int t = 0; t < nk; ++t) {
    __syncthreads();  // tile t landed (barrier drains vmcnt); half (t+1)&1 free
    if (t + 1 < nk) {
      int bo = ((t + 1) & 1) * 8192;
#pragma unroll
      for (int it = 0; it < 4; ++it) {
        gload16(gA[it] + (t + 1) * 64, As + bo + (wid * 32 + it * 8) * 64);
        gload16(gB[it] + (t + 1) * 64, Bs + bo + (wid * 32 + it * 8) * 64);
      }
    }
    const unsigned short* Asc = As + (t & 1) * 8192;
    const unsigned short* Bsc = Bs + (t & 1) * 8192;
    short8_t a[2][4], b[2][4];
#pragma unroll
    for (int ks = 0; ks < 2; ++ks) {
      int sw = ((ks * 4 + quad) ^ (l16 & 7)) * 8;
#pragma unroll
      for (int i = 0; i < 4; ++i) {
        a[ks][i] = *(const short8_t*)&Asc[(wm * 64 + i * 16 + l16) * 64 + sw];
        b[ks][i] = *(const short8_t*)&Bsc[(wn * 64 + i * 16 + l16) * 64 + sw];
      }
    }
#pragma unroll
    for (int ks = 0; ks < 2; ++ks)
#pragma unroll
      for (int i = 0; i < 4; ++i)
#pragma unroll
        for (int j = 0; j < 4; ++j)
          acc[i][j] = __builtin_amdgcn_mfma_f32_16x16x32_bf16(a[ks][i], b[ks][j], acc[i][j], 0, 0, 0);
  }
#pragma unroll
  for (int i = 0; i < 4; ++i)
#pragma unroll
    for (int j = 0; j < 4; ++j)
#pragma unroll
      for (int reg = 0; reg < 4; ++reg)
        C[(size_t)(m0 + wm * 64 + i * 16 + quad * 4 + reg) * ldc + n0 + wn * 64 + j * 16 + l16] =
            acc[i][j][reg];
}

// XCD-aware swizzle (T1): each XCD gets a contiguous id-chunk -> 2 consecutive by
// panels live in its private L2 instead of all 16. Requires nwg % 8 == 0 (512 ok).
__global__ __launch_bounds__(256) void gemm_bf16_v3(const unsigned short* __restrict__ A,
                                                    const unsigned short* __restrict__ Bt,
                                                    float* __restrict__ C,
                                                    int M, int N, int K, int ldc) {
  __shared__ unsigned short As[2 * 128 * 64];
  __shared__ unsigned short Bs[2 * 128 * 64];
  int lin = blockIdx.y * gridDim.x + blockIdx.x;
  int nwg = gridDim.x * gridDim.y;
  int q = nwg >> 3;
  int v = (lin & 7) * q + (lin >> 3);
  int bx = v % gridDim.x, by = v / gridDim.x;
  gemm_body(A, Bt, C, M, N, K, ldc, bx, by, As, Bs);
}

// ---------- fused q/k rmsnorm + rope (+q pool); grid (T, 8): each block does its kv's
// q-pair phase then k phase (halves dispatch count vs (T,16)) ----------
__global__ __launch_bounds__(128) void norm_rope_fused(const float* __restrict__ qkvf,
                                                       const float* __restrict__ qw,
                                                       const float* __restrict__ kw,
                                                       const float* __restrict__ cosT,
                                                       const float* __restrict__ sinT,
                                                       unsigned short* __restrict__ qbf,
                                                       unsigned short* __restrict__ qpool_bf,
                                                       unsigned short* __restrict__ kbf,
                                                       float* __restrict__ knorm) {
  int t = blockIdx.x, d = threadIdx.x;
  int kv = blockIdx.y;
  float cv = cosT[t * D_ + d], sv = sinT[t * D_ + d];
  // ---- phase 1: q pair ----
  {
    size_t i0 = (size_t)t * 4096 + (kv * G_) * D_ + d;
    float x0 = qkvf[i0], x1 = qkvf[i0 + D_];
    __shared__ float sred[2][2];
    float s0 = wave_sum(x0 * x0), s1 = wave_sum(x1 * x1);
    if ((d & 63) == 0) { sred[0][d >> 6] = s0; sred[1][d >> 6] = s1; }
    __syncthreads();
    float wv = qw[d];
    float n0 = x0 * rsqrtf((sred[0][0] + sred[0][1]) * (1.f / D_) + 1e-6f) * wv;
    float n1 = x1 * rsqrtf((sred[1][0] + sred[1][1]) * (1.f / D_) + 1e-6f) * wv;
    if (t >= TG0_) qpool_bf[((size_t)(t - TG0_) * KV_ + kv) * D_ + d] = f2bf(0.5f * (n0 + n1));
    __shared__ float sh[2][D_];
    sh[0][d] = n0; sh[1][d] = n1;
    __syncthreads();
    float r0 = (d < 64) ? -sh[0][d + 64] : sh[0][d - 64];
    float r1 = (d < 64) ? -sh[1][d + 64] : sh[1][d - 64];
    qbf[((size_t)(t * H_) + kv * G_) * D_ + d] = f2bf(n0 * cv + r0 * sv);
    qbf[((size_t)(t * H_) + kv * G_ + 1) * D_ + d] = f2bf(n1 * cv + r1 * sv);
  }
  __syncthreads();
  // ---- phase 2: k ----
  {
    float x = qkvf[(size_t)t * 4096 + 2048 + kv * D_ + d];
    __shared__ float sredk[2];
    float s0 = wave_sum(x * x);
    if ((d & 63) == 0) sredk[d >> 6] = s0;
    __syncthreads();
    float nk = x * rsqrtf((sredk[0] + sredk[1]) * (1.f / D_) + 1e-6f) * kw[d];
    knorm[(size_t)(t * KV_ + kv) * D_ + d] = nk;
    __shared__ float shk[D_];
    shk[d] = nk;
    __syncthreads();
    float rot = (d < 64) ? -shk[d + 64] : shk[d - 64];
    kbf[(size_t)(t * KV_ + kv) * D_ + d] = f2bf(nk * cv + rot * sv);
  }
}

// ---------- merged: castT for v (id<512) + k_blk mean (id>=512, 2 tasks/block) ----------
__global__ __launch_bounds__(256) void castT_kblk(const float* __restrict__ qkvf,
                                                  unsigned short* __restrict__ vt,
                                                  const float* __restrict__ knorm,
                                                  unsigned short* __restrict__ kblk_bf) {
  __shared__ unsigned short tile[64][72];
  int id = blockIdx.x, tid = threadIdx.x;
  if (id < 512) {
    castT_dev(qkvf + 3072, vt, T_, 1024, 4096, id & 15, id >> 4, tile, tid);
  } else {
    int task = (id - 512) * 2 + (tid >> 7);  // [0,256): n*8+kv
    int n = task >> 3, kv = task & 7, d = tid & 127;
    float s = 0.f;
    for (int i = 0; i < BS_; ++i) s += knorm[((size_t)(n * BS_ + i) * KV_ + kv) * D_ + d];
    kblk_bf[(size_t)(n * KV_ + kv) * D_ + d] = f2bf(s * (1.f / BS_));
  }
}

// ---------- fused rope for gk (rows<NB) and gq (rows>=NB, table offset TG0) ----------
__global__ __launch_bounds__(128) void rope_g_fused(float* __restrict__ gq, float* __restrict__ gk,
                                                    const float* __restrict__ cosG,
                                                    const float* __restrict__ sinG,
                                                    const float* __restrict__ cosB,
                                                    const float* __restrict__ sinB) {
  int r = blockIdx.x, kvh = blockIdx.y, d = threadIdx.x;
  float* x;
  size_t base;
  float c_, s_;
  if (r < NB_) {
    x = gk;
    base = (size_t)(r * KV_ + kvh) * GH_;
    c_ = cosB[r * GH_ + d]; s_ = sinB[r * GH_ + d];
  } else {
    int rr = r - NB_;
    x = gq;
    base = (size_t)(rr * KV_ + kvh) * GH_;
    c_ = cosG[(size_t)(TG0_ + rr) * GH_ + d]; s_ = sinG[(size_t)(TG0_ + rr) * GH_ + d];
  }
  __shared__ float sh[GH_];
  sh[d] = x[base + d];
  __syncthreads();
  float rot = (d < 64) ? -sh[d + 64] : sh[d - 64];
  x[base + d] = sh[d] * c_ + rot * s_;
}

// ---------- MFMA flash attention (round-9 proven, 49.2us) + gate-GEMM tail blocks.
// yy<64: attn, grid exactly 512 blocks = 2/CU resident (round-8/10 rebalances both
// regressed — frozen). yy>=64: the 106 gate-gemm blocks (gq = qpool@gwqT, gk =
// kblk@gwkT), LDS aliased onto Ks/Vs; they dispatch last and back-fill CUs whose
// short attn blocks exited early. Fixed-max softmax -> additive partials. ----------
__global__ __launch_bounds__(256, 2) void attn_gates(const unsigned short* __restrict__ qbf,
                                                     const unsigned short* __restrict__ kbf,
                                                     const unsigned short* __restrict__ vt,
                                                     float* __restrict__ pooled,
                                                     float* __restrict__ o_acc,
                                                     float* __restrict__ l_acc,
                                                     const unsigned short* __restrict__ Aq,
                                                     const unsigned short* __restrict__ Bq,
                                                     float* __restrict__ Cq,
                                                     const unsigned short* __restrict__ Ak,
                                                     const unsigned short* __restrict__ Bk,
                                                     float* __restrict__ Ck) {
  __shared__ unsigned short Ks[2][64 * 128];   // [key][chunk16 ^ (key&7)]
  __shared__ unsigned short Vs[2][128 * 64];   // [d][chunk16 ^ (d&7)]
  __shared__ unsigned short Ps[8][16 * 64];    // [wave*2+head][row][col8 ^ (row&7)]
  int kv = blockIdx.x;
  int yy = blockIdx.y;
  if (yy >= 64) {  // gate gemms: Ks(32KB)->As dbuf, Vs(32KB)->Bs dbuf
    int g2 = kv + ((yy - 64) << 3);
    unsigned short* As = &Ks[0][0];
    unsigned short* Bs = &Vs[0][0];
    if (g2 < 104)      gemm_body(Aq, Bq, Cq, 13312, 128, 128, 128, 0, g2, As, Bs);
    else if (g2 < 106) gemm_body(Ak, Bk, Ck, 256, 128, 128, 128, 0, g2 - 104, As, Bs);
    return;
  }
  int tile, c_lo, c_hi;
  if (yy < 32) { tile = yy;      c_lo = 0;                c_hi = (tile + 2) >> 1; }
  else         { tile = 63 - yy; c_lo = (tile + 2) >> 1;  c_hi = tile + 1; }
  int t0 = tile * 64;
  int tid = threadIdx.x;
  int wid = tid >> 6, lane = tid & 63;
  int quad = lane >> 4, l16 = lane & 15;

  const unsigned short* kbase[4];
  const unsigned short* vbase[4];
#pragma unroll
  for (int it = 0; it < 4; ++it) {
    int seg = wid * 4 + it;
    int krow = seg * 4 + (lane >> 4);
    int kchk = lane & 15;
    kbase[it] = kbf + ((size_t)krow * KV_ + kv) * D_ + ((kchk ^ (krow & 7)) << 3);
    int vrow = seg * 8 + (lane >> 3);
    int vchk = lane & 7;
    vbase[it] = vt + (size_t)(kv * 128 + vrow) * T_ + ((vchk ^ (vrow & 7)) << 3);
  }

  int tq = t0 + wid * 16 + l16;
  short8_t qf[2][4];
#pragma unroll
  for (int hh = 0; hh < 2; ++hh)
#pragma unroll
    for (int kb = 0; kb < 4; ++kb)
      qf[hh][kb] = *(const short8_t*)&qbf[((size_t)tq * H_ + kv * G_ + hh) * D_ + kb * 32 + quad * 8];

  const short one_bf = (short)0x3F80;
  short8_t ones = {one_bf, one_bf, one_bf, one_bf, one_bf, one_bf, one_bf, one_bf};

  int tbase = t0 + wid * 16 + quad * 4;
  float l_[2][4] = {};
  float pacc[2][2][4] = {};  // [head][half][reg]
  float4_t o[2][8];
#pragma unroll
  for (int hh = 0; hh < 2; ++hh)
#pragma unroll
    for (int j = 0; j < 8; ++j) o[hh][j] = (float4_t){0.f, 0.f, 0.f, 0.f};

  // prologue: stage chunk c_lo into buffer c_lo&1
#pragma unroll
  for (int it = 0; it < 4; ++it) {
    gload16(kbase[it] + (size_t)c_lo * 65536, &Ks[c_lo & 1][(wid * 4 + it) * 512]);
    gload16(vbase[it] + c_lo * 64, &Vs[c_lo & 1][(wid * 4 + it) * 512]);
  }
  for (int c = c_lo; c < c_hi; ++c) {
    __syncthreads();  // chunk c landed (vmcnt drained); buffer (c+1)&1 free
    if (c + 1 < c_hi) {
      int b = (c + 1) & 1;
#pragma unroll
      for (int it = 0; it < 4; ++it) {
        gload16(kbase[it] + (size_t)(c + 1) * 65536, &Ks[b][(wid * 4 + it) * 512]);
        gload16(vbase[it] + (c + 1) * 64, &Vs[b][(wid * 4 + it) * 512]);
      }
    }
    const unsigned short* Ksc = Ks[c & 1];
    const unsigned short* Vsc = Vs[c & 1];
    int half = c >> 4, cl = c & 15;

    // ---- QK^T for BOTH heads off one kf read ----
    float4_t s[2][4];
#pragma unroll
    for (int j = 0; j < 4; ++j) {
      float4_t a0 = (float4_t){0.f, 0.f, 0.f, 0.f};
      float4_t a1 = (float4_t){0.f, 0.f, 0.f, 0.f};
#pragma unroll
      for (int kb = 0; kb < 4; ++kb) {
        short8_t kf = *(const short8_t*)&Ksc[(j * 16 + l16) * 128 + (((kb * 4 + quad) ^ (l16 & 7)) << 3)];
        a0 = __builtin_amdgcn_mfma_f32_16x16x32_bf16(qf[0][kb], kf, a0, 0, 0, 0);
        a1 = __builtin_amdgcn_mfma_f32_16x16x32_bf16(qf[1][kb], kf, a1, 0, 0, 0);
      }
      s[0][j] = a0;
      s[1][j] = a1;
    }
    // ---- p = exp(logit - MFIX); causal mask only on diagonal chunk ----
#pragma unroll
    for (int hh = 0; hh < 2; ++hh) {
      if (c == tile) {
#pragma unroll
        for (int reg = 0; reg < 4; ++reg) {
          int trow = tbase + reg;
#pragma unroll
          for (int j = 0; j < 4; ++j) {
            float p = __expf(s[hh][j][reg] * SCALE_ - MFIX_);
            s[hh][j][reg] = (c * 64 + j * 16 + l16 <= trow) ? p : 0.f;
          }
        }
      } else {
#pragma unroll
        for (int j = 0; j < 4; ++j)
#pragma unroll
          for (int reg = 0; reg < 4; ++reg)
            s[hh][j][reg] = __expf(s[hh][j][reg] * SCALE_ - MFIX_);
      }
      // write P (C layout) -> per-wave-per-head LDS, XOR-swizzled stride 64
#pragma unroll
      for (int j = 0; j < 4; ++j)
#pragma unroll
        for (int reg = 0; reg < 4; ++reg) {
          int r = quad * 4 + reg;
          Ps[wid * 2 + hh][r * 64 + ((j * 16 + l16) ^ ((r & 7) << 3))] = f2bf(s[hh][j][reg]);
        }
    }
    // ---- PV + row-sum for BOTH heads off one vf read ----
    float4_t pool[2] = {(float4_t){0.f, 0.f, 0.f, 0.f}, (float4_t){0.f, 0.f, 0.f, 0.f}};
#pragma unroll
    for (int ks = 0; ks < 2; ++ks) {
      int psw = l16 * 64 + (((ks * 4 + quad) ^ (l16 & 7)) << 3);
      short8_t pf0 = *(const short8_t*)&Ps[wid * 2 + 0][psw];
      short8_t pf1 = *(const short8_t*)&Ps[wid * 2 + 1][psw];
      pool[0] = __builtin_amdgcn_mfma_f32_16x16x32_bf16(pf0, ones, pool[0], 0, 0, 0);
      pool[1] = __builtin_amdgcn_mfma_f32_16x16x32_bf16(pf1, ones, pool[1], 0, 0, 0);
#pragma unroll
      for (int jt = 0; jt < 8; ++jt) {
        short8_t vf = *(const short8_t*)&Vsc[(jt * 16 + l16) * 64 + (((ks * 4 + quad) ^ (l16 & 7)) << 3)];
        o[0][jt] = __builtin_amdgcn_mfma_f32_16x16x32_bf16(pf0, vf, o[0][jt], 0, 0, 0);
        o[1][jt] = __builtin_amdgcn_mfma_f32_16x16x32_bf16(pf1, vf, o[1][jt], 0, 0, 0);
      }
    }
#pragma unroll
    for (int hh = 0; hh < 2; ++hh)
#pragma unroll
      for (int reg = 0; reg < 4; ++reg) {
        l_[hh][reg] += pool[hh][reg];
        if (l16 == cl) pacc[hh][half][reg] = pool[hh][reg];
      }
  }
  // ---- epilogue: raw additive partials ----
#pragma unroll
  for (int hh = 0; hh < 2; ++hh) {
    int h = kv * G_ + hh;
    // pooled RAW, disjoint columns per piece
#pragma unroll
    for (int reg = 0; reg < 4; ++reg) {
      int trow = tbase + reg;
      if (l16 >= c_lo && l16 < c_hi)
        pooled[((size_t)h * T_ + trow) * NB_ + l16] = pacc[hh][0][reg];
      if (16 + l16 >= c_lo && 16 + l16 < c_hi)
        pooled[((size_t)h * T_ + trow) * NB_ + 16 + l16] = pacc[hh][1][reg];
    }
    // o/l partials: fp32 atomic accumulate (pieces of a tile run concurrently)
#pragma unroll
    for (int jt = 0; jt < 8; ++jt)
#pragma unroll
      for (int reg = 0; reg < 4; ++reg)
        atomicAdd(&o_acc[(((size_t)h * T_) + tbase + reg) * D_ + jt * 16 + l16], o[hh][jt][reg]);
    if (l16 == 0) {
#pragma unroll
      for (int reg = 0; reg < 4; ++reg)
        atomicAdd(&l_acc[(size_t)h * T_ + tbase + reg], l_[hh][reg]);
    }
  }
}

// ---------- gate loss body, LDS-staged gk (round-7 proven) ----------
__device__ __forceinline__ void gate_loss_body(const float* __restrict__ gq,
                                               const float* __restrict__ gk,
                                               const float* __restrict__ pooled,
                                               const float* __restrict__ l_acc,
                                               float* __restrict__ klsum,
                                               int kv, int yblk, float4* gks4) {
  int tid = threadIdx.x;
  // cooperative stage: 1024 float4s, 4 per thread
#pragma unroll
  for (int p = 0; p < 4; ++p) {
    int f = p * 256 + tid;
    int n = f >> 5, d4 = f & 31;
    gks4[n * 32 + (d4 ^ (n & 7))] =
        *(const float4*)(gk + ((size_t)n * KV_ + kv) * GH_ + d4 * 4);
  }
  __syncthreads();
  int sub = tid >> 5;  // 0..7
  int n = tid & 31;
  int tloc = yblk * 8 + sub;
  bool act = tloc < (T_ - START_);
  int t = START_ + (act ? tloc : 0);
  const float4* a = (const float4*)(gq + ((size_t)(t - TG0_) * KV_ + kv) * GH_);
  float dot = 0.f;
#pragma unroll
  for (int d4 = 0; d4 < 32; ++d4) {
    float4 av = a[d4];
    float4 bv = gks4[n * 32 + (d4 ^ (n & 7))];
    dot += av.x * bv.x + av.y * bv.y + av.z * bv.z + av.w * bv.w;
  }
  bool valid = (t / BS_) >= n;
  float score = valid ? dot * SCALE_ : -1e9f;
  float M = score;
#pragma unroll
  for (int o = 16; o > 0; o >>= 1) M = fmaxf(M, __shfl_xor(M, o, 64));
  float e = __expf(score - M);
  float Z = e;
#pragma unroll
  for (int o = 16; o > 0; o >>= 1) Z += __shfl_xor(Z, o, 64);
  float logZ = M + logf(Z);
  float g = 0.f;
  if (valid) {
    float rl0 = 1.f / l_acc[(size_t)(kv * G_) * T_ + t];
    float rl1 = 1.f / l_acc[(size_t)(kv * G_ + 1) * T_ + t];
    float p0 = pooled[((size_t)(kv * G_) * T_ + t) * NB_ + n] * rl0;
    float p1 = pooled[((size_t)(kv * G_ + 1) * T_ + t) * NB_ + n] * rl1;
    g = fmaxf(p0, p1);
  }
  float gs = g;
#pragma unroll
  for (int o = 16; o > 0; o >>= 1) gs += __shfl_xor(gs, o, 64);
  float tgt = g / (gs + 1e-9f);
  float kl = (tgt > 0.f) ? tgt * (logf(tgt) - (score - logZ)) : 0.f;
  float ks = kl;
#pragma unroll
  for (int o = 16; o > 0; o >>= 1) ks += __shfl_xor(ks, o, 64);
  if (n == 0 && act) klsum[kv * (T_ - START_) + tloc] = ks;
}

// ---------- merged: gate loss (id<1640, dispatched first) + attn_combine (id>=1640) ----------
__global__ __launch_bounds__(256) void combine_gate(const float* __restrict__ o_acc,
                                                    const float* __restrict__ l_acc,
                                                    unsigned short* __restrict__ attnb,
                                                    const float* __restrict__ gq,
                                                    const float* __restrict__ gk,
                                                    const float* __restrict__ pooled,
                                                    float* __restrict__ klsum) {
  __shared__ float4 gks4[1024];
  int id = blockIdx.x;
  if (id < 1640) {
    gate_loss_body(gq, gk, pooled, l_acc, klsum, id & 7, id >> 3, gks4);
  } else {
    int gid = (id - 1640) * 256 + threadIdx.x;  // [0, 1048576) float4 units
    int row = gid >> 5, q4 = gid & 31;          // row = h*2048 + t
    int h = row >> 11, t = row & 2047;
    float inv = 1.f / l_acc[row];
    float4 a = ((const float4*)o_acc)[gid];
    ushort4_t ov = {f2bf(a.x * inv), f2bf(a.y * inv), f2bf(a.z * inv), f2bf(a.w * inv)};
    *(ushort4_t*)(attnb + (size_t)t * (H_ * D_) + h * D_ + q4 * 4) = ov;
  }
}

// ---------- merged: Wo GEMM (y<16, XCD-swizzled) + finalize_loss (y==16, x==0) ----------
__global__ __launch_bounds__(256) void wo_gemm_final(const unsigned short* __restrict__ A,
                                                     const unsigned short* __restrict__ Bt,
                                                     float* __restrict__ C,
                                                     const float* __restrict__ klsum,
                                                     float* __restrict__ lout) {
  __shared__ unsigned short As[2 * 128 * 64];
  __shared__ unsigned short Bs[2 * 128 * 64];
  if (blockIdx.y < 16) {
    int lin = blockIdx.y * 16 + blockIdx.x;   // [0,256)
    int v = (lin & 7) * 32 + (lin >> 3);      // XCD swizzle, bijective on [0,256)
    gemm_body(A, Bt, C, 2048, 2048, 2048, 2048, v & 15, v >> 4, As, Bs);
  } else if (blockIdx.x == 0) {
    const int n = KV_ * (T_ - START_);
    float s = 0.f;
    for (int i = threadIdx.x; i < n; i += 256) s += klsum[i];
    s = wave_sum(s);
    float* sh = (float*)As;
    if ((threadIdx.x & 63) == 0) sh[threadIdx.x >> 6] = s;
    __syncthreads();
    if (threadIdx.x == 0)
      lout[0] = (sh[0] + sh[1] + sh[2] + sh[3]) * (1.f / ((float)(T_ - START_) * NB_));
  }
}

extern "C" void kernel_launch(void* const* d_in, const int* in_sizes, int n_in,
                              void* d_out, int out_size, void* d_ws, size_t ws_size,
                              hipStream_t stream) {
  const float* hs   = (const float*)d_in[0];
  const float* Wq   = (const float*)d_in[1];
  const float* Wk   = (const float*)d_in[2];
  const float* Wv   = (const float*)d_in[3];
  const float* Wo   = (const float*)d_in[4];
  const float* qw   = (const float*)d_in[5];
  const float* kw   = (const float*)d_in[6];
  const float* gwq  = (const float*)d_in[7];
  const float* gwk  = (const float*)d_in[8];
  const float* cosT = (const float*)d_in[9];
  const float* sinT = (const float*)d_in[10];
  const float* cosG = (const float*)d_in[11];
  const float* sinG = (const float*)d_in[12];
  const float* cosB = (const float*)d_in[13];
  const float* sinB = (const float*)d_in[14];
  float* out = (float*)d_out;
  float* ws = (float*)d_ws;
  const size_t MEG = 1048576;

  // ---- workspace layout (float offsets), lifetime-aliased ----
  float*          qkvf     = ws;                                 // [0,8M): [T][4096] fp32
  unsigned short* attnb    = (unsigned short*)ws;                //   alias after qkvf consumed
  float*          pooled   = ws + 2 * MEG;                       //   alias
  float*          klsum    = ws + 3 * MEG;                       //   alias (13112 floats)
  float*          l_acc    = ws + 3 * MEG + 65536;               //   alias: [H][T] row-sum l
  float*          o_acc    = ws + 4 * MEG;                       //   alias: [H][T][128] fp32 (16MB)
  unsigned short* WqkvT    = (unsigned short*)(ws + 8 * MEG);    // [8M,12M): 8M ushorts
  unsigned short* qbf      = WqkvT;                              //   alias after qkv gemm
  unsigned short* kbf      = WqkvT + 4 * MEG;
  unsigned short* vt       = WqkvT + 6 * MEG;
  unsigned short* hsb      = (unsigned short*)(ws + 12 * MEG);   // [12M,14M)
  float*          knorm    = ws + 12 * MEG;                      //   alias after qkv gemm
  unsigned short* WoT      = (unsigned short*)(ws + 14 * MEG);   // [14M,16M)
  unsigned short* qpool_bf = (unsigned short*)(ws + 16 * MEG);   // [16M,...)
  float*          gq       = ws + 17 * MEG;
  unsigned short* kblk_bf  = (unsigned short*)(ws + 18 * MEG + 786432);
  float*          gk       = ws + 18 * MEG + 819200;
  unsigned short* gwqT     = (unsigned short*)(ws + 18 * MEG + 851968);
  unsigned short* gwkT     = (unsigned short*)(ws + 18 * MEG + 860160);

  prep_cast<<<7176, 256, 0, stream>>>(hs, Wq, Wk, Wv, Wo, gwq, gwk, hsb, WqkvT, WoT, gwqT, gwkT);
  gemm_bf16_v3<<<dim3(32, 16), 256, 0, stream>>>(hsb, WqkvT, qkvf, 2048, 4096, 2048, 4096);
  norm_rope_fused<<<dim3(T_, 8), 128, 0, stream>>>(qkvf, qw, kw, cosT, sinT, qbf, qpool_bf,
                                                   kbf, knorm);
  castT_kblk<<<640, 256, 0, stream>>>(qkvf, vt, knorm, kblk_bf);
  // qkvf fully consumed -> zero the atomic accumulators living in its footprint
  hipMemsetAsync(o_acc, 0, (size_t)4 * MEG * sizeof(float), stream);
  hipMemsetAsync(l_acc, 0, (size_t)H_ * T_ * sizeof(float), stream);
  attn_gates<<<dim3(KV_, 78), 256, 0, stream>>>(qbf, kbf, vt, pooled, o_acc, l_acc,
                                                qpool_bf, gwqT, gq, kblk_bf, gwkT, gk);
  rope_g_fused<<<dim3(NB_ + (T_ - TG0_), KV_), 128, 0, stream>>>(gq, gk, cosG, sinG, cosB, sinB);
  combine_gate<<<1640 + 4096, 256, 0, stream>>>(o_acc, l_acc, attnb, gq, gk, pooled, klsum);
  wo_gemm_final<<<dim3(16, 17), 256, 0, stream>>>(attnb, WoT, out, klsum, out + (size_t)T_ * HID_);
  finalize_loss:;
}